// Round 9
// baseline (208.414 us; speedup 1.0000x reference)
//
#include <hip/hip_runtime.h>
#include <hip/hip_bf16.h>

#define BB 16
#define NN 4096
#define DD 64
#define NM1 4095

typedef __bf16 bf16x8 __attribute__((ext_vector_type(8)));
typedef float f32x4 __attribute__((ext_vector_type(4)));

typedef __attribute__((address_space(1))) const void gas_void;
typedef __attribute__((address_space(3))) void las_void;

// ws layout:
//   [0]                  float mx[4096]          (16 KB)  -- zeroed via memsetAsync
//   [16384]              float ss[4096]          (16 KB)  -- zeroed via memsetAsync
//   [32768]              __bf16 XT[16][64][4096] ( 8 MiB)
//   [32768 + 8 MiB]      __bf16 A16[4096][4096]  (32 MiB)

// ---------------------------------------------------------------------------
// Kernel 1: flat scatter build. j-major: lane-consecutive loads AND stores.
// ---------------------------------------------------------------------------
__global__ __launch_bounds__(256) void build_kernel(
    const float* __restrict__ inc, float* __restrict__ out_inc,
    __bf16* __restrict__ A16, float* __restrict__ mxa, float* __restrict__ ssa)
{
    int t = threadIdx.x;
    int base = blockIdx.x << 12;                 // 4096 elems per block
    int rA = (int)((unsigned)base / NM1);        // block spans rows {rA, rA+1}
    float pm0 = 0.f, ps0 = 0.f, pm1 = 0.f, ps1 = 0.f;
    #pragma unroll
    for (int j = 0; j < 16; ++j) {
        int f = base + j * 256 + t;              // < 2^24, exact coverage
        int i = (int)((unsigned)f / NM1);
        int c = f - i * NM1;
        float x = inc[f];
        float w = x > 0.01f ? x : 0.f;
        int dst = f + i + (c >= i);              // i*4096 + c + (c>=i)
        out_inc[dst] = w;
        A16[dst] = (__bf16)w;
        if (i == rA) { pm0 = fmaxf(pm0, w); ps0 += w * w; }
        else         { pm1 = fmaxf(pm1, w); ps1 += w * w; }
    }
    #pragma unroll
    for (int off = 32; off; off >>= 1) {
        pm0 = fmaxf(pm0, __shfl_down(pm0, off));
        ps0 += __shfl_down(ps0, off);
        pm1 = fmaxf(pm1, __shfl_down(pm1, off));
        ps1 += __shfl_down(ps1, off);
    }
    __shared__ float sm0[4], sq0[4], sm1[4], sq1[4];
    int wid = t >> 6;
    if ((t & 63) == 0) { sm0[wid] = pm0; sq0[wid] = ps0; sm1[wid] = pm1; sq1[wid] = ps1; }
    __syncthreads();
    if (t == 0) {
        float m0v = fmaxf(fmaxf(sm0[0], sm0[1]), fmaxf(sm0[2], sm0[3]));
        float s0v = sq0[0] + sq0[1] + sq0[2] + sq0[3];
        float m1v = fmaxf(fmaxf(sm1[0], sm1[1]), fmaxf(sm1[2], sm1[3]));
        float s1v = sq1[0] + sq1[1] + sq1[2] + sq1[3];
        atomicMax((unsigned*)(mxa + rA), __float_as_uint(m0v));  // w >= 0
        atomicAdd(ssa + rA, s0v);
        int rB = rA + 1;
        if (rB < NN) {
            atomicMax((unsigned*)(mxa + rB), __float_as_uint(m1v));
            atomicAdd(ssa + rB, s1v);
        }
    }
}

// ---------------------------------------------------------------------------
// Kernel 2: XT[b][d][n] = (bf16)X[b][n][d]  (64x64 tiles via LDS) + diagonal
// ---------------------------------------------------------------------------
__global__ __launch_bounds__(256) void xt_kernel(
    const float* __restrict__ X, __bf16* __restrict__ XT,
    float* __restrict__ out_inc, __bf16* __restrict__ A16)
{
    __shared__ __bf16 tile[64 * 72];             // stride 72 elems = 144 B
    int t = threadIdx.x;
    int ntile = blockIdx.x, b = blockIdx.y;
    int n = t >> 2, q = t & 3;
    const float* src = X + ((size_t)b * NN + ntile * 64 + n) * DD + q * 16;
    #pragma unroll
    for (int v = 0; v < 4; ++v) {
        f32x4 u = *(const f32x4*)(src + v * 4);
        #pragma unroll
        for (int j = 0; j < 4; ++j) {
            int d = q * 16 + v * 4 + j;
            tile[d * 72 + n] = (__bf16)u[j];
        }
    }
    __syncthreads();
    int d = t >> 2;
    __bf16* dst = XT + ((size_t)b * DD + d) * NN + ntile * 64 + q * 16;
    *(bf16x8*)dst       = *(bf16x8*)&tile[d * 72 + q * 16];
    *(bf16x8*)(dst + 8) = *(bf16x8*)&tile[d * 72 + q * 16 + 8];
    if (b == 0 && t < 64) {                      // diagonal of W + I
        int r = ntile * 64 + t;
        out_inc[(size_t)r * NN + r] = 1.0f;
        A16[(size_t)r * NN + r] = (__bf16)1.0f;
    }
}

// ---------------------------------------------------------------------------
// Kernel 3: acc = A16 @ X[b] via MFMA. R4 structure (best verified: 43.4us)
//   + serial-section squeeze:
//   - stage(kt+3) issued BEFORE compute(kt) (hazard covered by barrier#kt)
//   - R = rproj+I pre-staged into dedicated LDS region during prologue
//   - mxa/ssa prefetched to regs at start (oldest in vmcnt queue -> ledger ok)
//   - XA (X rows) loads issued before compute(3); phase-2 only writes
//   block = 128 rows x 64 cols x 2 batches; 512 thr / 8 waves (2/SIMD);
//   wave = 32 rows x 64 cols of one batch. 4 x 32 KB LDS buffers, depth-3,
//   ONE s_barrier + counted vmcnt(8) per k-step, setprio around MFMA.
// ---------------------------------------------------------------------------
__global__ __launch_bounds__(512, 2) void gemm_loss_kernel(
    const __bf16* __restrict__ A16, const __bf16* __restrict__ XT,
    const float* __restrict__ X, const float* __restrict__ rproj,
    const float* __restrict__ mxa, const float* __restrict__ ssa,
    float* __restrict__ loss)
{
    // buffer c at smem + c*16384:  A[128][64] then X[2][64][64] (flat [128][64])
    __shared__ __bf16 smem[4 * 16384];           // 128 KB
    __shared__ __bf16 Rr[64 * 64];               // 8 KB: r + I, swizzled
    __shared__ float  msl[256];                  // mx[128] then ss[128]

    const int t = threadIdx.x;
    const int wave = t >> 6, lane = t & 63;
    const int quad = lane >> 4, ln = lane & 15;
    const int sr = lane >> 3, so = lane & 7;     // staging row-in-group / octet
    const int bq = wave >> 2;                    // batch within pair (0/1)
    const int wr = (wave & 3) << 5;              // wave row offset: 0/32/64/96
    const int m0 = blockIdx.x * 128;
    const int b0 = blockIdx.y * 2;

    const __bf16* Abase = A16 + (size_t)m0 * NN;
    const __bf16* XTb   = XT + (size_t)b0 * DD * NN;   // 2 batches, flat 128 rows

#define FENCE() asm volatile("" ::: "memory")
#define VMCNT(N) asm volatile("s_waitcnt vmcnt(" #N ")" ::: "memory")
#define BAR() do { __builtin_amdgcn_s_barrier(); \
                   __builtin_amdgcn_sched_barrier(0); } while (0)

    // ---- early prefetches (issued before stages -> oldest in vmcnt queue,
    //      drained by the compiler-inserted waits before their first use) ----
    float mxv = 0.f, ssv = 0.f;
    if (t < 128) { mxv = mxa[m0 + t]; ssv = ssa[m0 + t]; }
    f32x4 rv0, rv1, rv2, rv3;
    const int rr2 = t >> 2, q2 = t & 3;          // rr2 in [0,128); R uses <64
    if (t < 256) {
        const float* rs = rproj + (size_t)rr2 * DD + q2 * 16;
        rv0 = *(const f32x4*)(rs);
        rv1 = *(const f32x4*)(rs + 4);
        rv2 = *(const f32x4*)(rs + 8);
        rv3 = *(const f32x4*)(rs + 12);
    }
    FENCE();                                     // pin prefetch loads before stages

    f32x4 acc[2][4];
    f32x4 zero = {0.f, 0.f, 0.f, 0.f};
    #pragma unroll
    for (int mt = 0; mt < 2; ++mt)
        #pragma unroll
        for (int ct = 0; ct < 4; ++ct) acc[mt][ct] = zero;

    // stage one 64-wide k-step into buffer `buf`: A 16 KB + X 16 KB,
    // 4 global_load_lds (16 B) per thread, XOR-octet pre-swizzled source.
    auto stage = [&](int buf, int kt) {
        __bf16* bA = smem + buf * 16384;
        __bf16* bX = bA + 8192;
        const int k0 = kt << 6;
        #pragma unroll
        for (int p = 0; p < 2; ++p) {
            const int r0 = (p << 6) + (wave << 3);   // wave-uniform 8-row group
            const int r  = r0 + sr;
            const int og = so ^ (r & 7);             // LDS[r][o] = G[r][o^(r&7)]
            __builtin_amdgcn_global_load_lds(
                (gas_void*)(Abase + (size_t)r * NN + k0 + (og << 3)),
                (las_void*)(bA + r0 * 64), 16, 0, 0);
            __builtin_amdgcn_global_load_lds(
                (gas_void*)(XTb + (size_t)r * NN + k0 + (og << 3)),
                (las_void*)(bX + r0 * 64), 16, 0, 0);
        }
    };

    auto compute = [&](int buf) {
        const __bf16* bA = smem + buf * 16384;
        const __bf16* bX = bA + 8192 + (bq << 12);   // this wave's batch [64][64]
        __builtin_amdgcn_s_setprio(1);
        #pragma unroll
        for (int kk = 0; kk < 64; kk += 32) {
            const int oc = (kk >> 3) + quad;
            bf16x8 af[2], bfr[4];
            #pragma unroll
            for (int mt = 0; mt < 2; ++mt) {
                const int r = wr + mt * 16 + ln;
                af[mt] = *(const bf16x8*)&bA[r * 64 + ((oc ^ (r & 7)) << 3)];
            }
            #pragma unroll
            for (int ct = 0; ct < 4; ++ct) {
                const int n = ct * 16 + ln;
                bfr[ct] = *(const bf16x8*)&bX[n * 64 + ((oc ^ (n & 7)) << 3)];
            }
            #pragma unroll
            for (int mt = 0; mt < 2; ++mt)
                #pragma unroll
                for (int ct = 0; ct < 4; ++ct)
                    acc[mt][ct] = __builtin_amdgcn_mfma_f32_16x16x32_bf16(
                        af[mt], bfr[ct], acc[mt][ct], 0, 0, 0);
        }
        __builtin_amdgcn_s_setprio(0);
    };

    const int NT = NN / 64;                      // 64 k-steps
    stage(0, 0); FENCE();
    stage(1, 1); FENCE();
    stage(2, 2); FENCE();

    // R = rproj + I into dedicated region (overlaps pipeline prologue).
    // Compiler inserts the precise vmcnt wait for rv* before these ds_writes.
    if (t < 256) {
        #pragma unroll
        for (int v = 0; v < 4; ++v) {
            f32x4 u = v == 0 ? rv0 : v == 1 ? rv1 : v == 2 ? rv2 : rv3;
            #pragma unroll
            for (int j = 0; j < 4; ++j) {
                const int d = q2 * 16 + v * 4 + j;
                float val = u[j] + (d == rr2 ? 1.0f : 0.0f);   // r + I
                Rr[d * 64 + (((rr2 >> 3) ^ (d & 7)) << 3) + (rr2 & 7)] = (__bf16)val;
            }
        }
    }

    for (int kt = 0; kt < NT - 3; ++kt) {        // kt = 0..60
        VMCNT(8);                                // outstanding kt..kt+2 (12); drain kt
        BAR();
        stage((kt + 3) & 3, kt + 3);             // buffer last read by compute(kt-1)
        compute(kt & 3);
    }
    VMCNT(8);  BAR(); compute(1);                // kt = 61 (outstanding 61..63)
    VMCNT(4);  BAR(); compute(2);                // kt = 62
    VMCNT(0);  BAR();                            // kt = 63: queue empty

    // XA prefetch: X rows for both batches, in flight under compute(3)
    f32x4 xa[2][2][2];                           // [bb][v][half], static idx
    const int rr = t >> 2, q = t & 3;            // rr in [0,128)
    {
        #pragma unroll
        for (int bb = 0; bb < 2; ++bb) {
            const float* xs = X + ((size_t)(b0 + bb) * NN + m0 + rr) * DD + q * 16;
            #pragma unroll
            for (int v = 0; v < 2; ++v) {
                xa[bb][v][0] = *(const f32x4*)(xs + v * 8);
                xa[bb][v][1] = *(const f32x4*)(xs + v * 8 + 4);
            }
        }
    }
    compute(3);

#undef BAR
#undef VMCNT
#undef FENCE

    __syncthreads();                             // all compute done before reuse

    // ---- phase 2: write XA[2][128][64] from prefetched regs; publish msl ----
    {
        #pragma unroll
        for (int bb = 0; bb < 2; ++bb) {
            __bf16* XA = smem + bb * 8192;
            #pragma unroll
            for (int v = 0; v < 2; ++v) {
                f32x4 u0 = xa[bb][v][0];
                f32x4 u1 = xa[bb][v][1];
                bf16x8 w;
                #pragma unroll
                for (int j = 0; j < 4; ++j) { w[j] = (__bf16)u0[j]; w[j + 4] = (__bf16)u1[j]; }
                const int o = (q * 2 + v) ^ (rr & 7);
                *(bf16x8*)&XA[rr * 64 + o * 8] = w;
            }
        }
        if (t < 128) { msl[t] = mxv; msl[128 + t] = ssv; }
    }
    __syncthreads();

    // ---- xp phase accumulates into -acc: dif = X@(r+I) - acc ----
    #pragma unroll
    for (int mt = 0; mt < 2; ++mt)
        #pragma unroll
        for (int ct = 0; ct < 4; ++ct) acc[mt][ct] = -acc[mt][ct];

    {
        const __bf16* XA = smem + bq * 8192;
        #pragma unroll
        for (int kk = 0; kk < DD; kk += 32) {
            const int oc = (kk >> 3) + quad;
            bf16x8 af[2], bfr[4];
            #pragma unroll
            for (int mt = 0; mt < 2; ++mt) {
                const int r = wr + mt * 16 + ln;
                af[mt] = *(const bf16x8*)&XA[r * 64 + ((oc ^ (r & 7)) << 3)];
            }
            #pragma unroll
            for (int ct = 0; ct < 4; ++ct) {
                const int n = ct * 16 + ln;
                bfr[ct] = *(const bf16x8*)&Rr[n * 64 + ((oc ^ (n & 7)) << 3)];
            }
            #pragma unroll
            for (int mt = 0; mt < 2; ++mt)
                #pragma unroll
                for (int ct = 0; ct < 4; ++ct)
                    acc[mt][ct] = __builtin_amdgcn_mfma_f32_16x16x32_bf16(
                        af[mt], bfr[ct], acc[mt][ct], 0, 0, 0);
        }
    }

    // ---- epilogue: C/D layout col=ln, row=quad*4+reg; wave owns full rows ----
    #pragma unroll
    for (int mt = 0; mt < 2; ++mt) {
        #pragma unroll
        for (int rg = 0; rg < 4; ++rg) {
            float s = 0.f;
            #pragma unroll
            for (int ct = 0; ct < 4; ++ct) {
                float d = acc[mt][ct][rg];
                s += d * d;
            }
            s += __shfl_xor(s, 1);
            s += __shfl_xor(s, 2);
            s += __shfl_xor(s, 4);
            s += __shfl_xor(s, 8);
            if (ln == 0) {
                int rloc = wr + mt * 16 + quad * 4 + rg;
                loss[(size_t)(b0 + bq) * NN + m0 + rloc] =
                    0.2f * sqrtf(s) + msl[rloc] + 0.001f * sqrtf(msl[128 + rloc]);
            }
        }
    }
}

extern "C" void kernel_launch(void* const* d_in, const int* in_sizes, int n_in,
                              void* d_out, int out_size, void* d_ws, size_t ws_size,
                              hipStream_t stream) {
    const float* X   = (const float*)d_in[0];   // [B][N][D] f32
    const float* r   = (const float*)d_in[1];   // [D][D] f32
    const float* inc = (const float*)d_in[2];   // [N][N-1] f32
    float* out      = (float*)d_out;
    float* out_loss = out;                       // [B][N]
    float* out_inc  = out + (size_t)BB * NN;     // [N][N]

    char* ws = (char*)d_ws;
    float*  mxa = (float*)ws;                               // 16 KB
    float*  ssa = (float*)(ws + 16384);                     // 16 KB
    __bf16* XT  = (__bf16*)(ws + 32768);                    //  8 MiB
    __bf16* A16 = (__bf16*)(ws + 32768 + (size_t)8 * 1024 * 1024);  // 32 MiB

    hipMemsetAsync(mxa, 0, 32768, stream);      // zero mx/ss accumulators

    hipLaunchKernelGGL(build_kernel, dim3(NM1), dim3(256), 0, stream,
                       inc, out_inc, A16, mxa, ssa);
    hipLaunchKernelGGL(xt_kernel, dim3(NN / 64, BB), dim3(256), 0, stream,
                       X, XT, out_inc, A16);
    hipLaunchKernelGGL(gemm_loss_kernel, dim3(NN / 128, BB / 2), dim3(512), 0, stream,
                       A16, XT, X, r, mxa, ssa, out_loss);
}

// Round 10
// 190.879 us; speedup vs baseline: 1.0919x; 1.0919x over previous
//
#include <hip/hip_runtime.h>
#include <hip/hip_bf16.h>

#define BB 16
#define NN 4096
#define DD 64
#define NM1 4095

typedef __bf16 bf16x8 __attribute__((ext_vector_type(8)));
typedef float f32x4 __attribute__((ext_vector_type(4)));

typedef __attribute__((address_space(1))) const void gas_void;
typedef __attribute__((address_space(3))) void las_void;

// ws layout:
//   [0]                  float mx[4096]          (16 KB)  -- zeroed via memsetAsync
//   [16384]              float ss[4096]          (16 KB)  -- zeroed via memsetAsync
//   [32768]              __bf16 XT[16][64][4096] ( 8 MiB)
//   [32768 + 8 MiB]      __bf16 A16[4096][4096]  (32 MiB)

// ---------------------------------------------------------------------------
// Kernel 1: flat scatter build. j-major: lane-consecutive loads AND stores.
// ---------------------------------------------------------------------------
__global__ __launch_bounds__(256) void build_kernel(
    const float* __restrict__ inc, float* __restrict__ out_inc,
    __bf16* __restrict__ A16, float* __restrict__ mxa, float* __restrict__ ssa)
{
    int t = threadIdx.x;
    int base = blockIdx.x << 12;                 // 4096 elems per block
    int rA = (int)((unsigned)base / NM1);        // block spans rows {rA, rA+1}
    float pm0 = 0.f, ps0 = 0.f, pm1 = 0.f, ps1 = 0.f;
    #pragma unroll
    for (int j = 0; j < 16; ++j) {
        int f = base + j * 256 + t;              // < 2^24, exact coverage
        int i = (int)((unsigned)f / NM1);
        int c = f - i * NM1;
        float x = inc[f];
        float w = x > 0.01f ? x : 0.f;
        int dst = f + i + (c >= i);              // i*4096 + c + (c>=i)
        out_inc[dst] = w;
        A16[dst] = (__bf16)w;
        if (i == rA) { pm0 = fmaxf(pm0, w); ps0 += w * w; }
        else         { pm1 = fmaxf(pm1, w); ps1 += w * w; }
    }
    #pragma unroll
    for (int off = 32; off; off >>= 1) {
        pm0 = fmaxf(pm0, __shfl_down(pm0, off));
        ps0 += __shfl_down(ps0, off);
        pm1 = fmaxf(pm1, __shfl_down(pm1, off));
        ps1 += __shfl_down(ps1, off);
    }
    __shared__ float sm0[4], sq0[4], sm1[4], sq1[4];
    int wid = t >> 6;
    if ((t & 63) == 0) { sm0[wid] = pm0; sq0[wid] = ps0; sm1[wid] = pm1; sq1[wid] = ps1; }
    __syncthreads();
    if (t == 0) {
        float m0v = fmaxf(fmaxf(sm0[0], sm0[1]), fmaxf(sm0[2], sm0[3]));
        float s0v = sq0[0] + sq0[1] + sq0[2] + sq0[3];
        float m1v = fmaxf(fmaxf(sm1[0], sm1[1]), fmaxf(sm1[2], sm1[3]));
        float s1v = sq1[0] + sq1[1] + sq1[2] + sq1[3];
        atomicMax((unsigned*)(mxa + rA), __float_as_uint(m0v));  // w >= 0
        atomicAdd(ssa + rA, s0v);
        int rB = rA + 1;
        if (rB < NN) {
            atomicMax((unsigned*)(mxa + rB), __float_as_uint(m1v));
            atomicAdd(ssa + rB, s1v);
        }
    }
}

// ---------------------------------------------------------------------------
// Kernel 2: XT[b][d][n] = (bf16)X[b][n][d]  (64x64 tiles via LDS) + diagonal
// ---------------------------------------------------------------------------
__global__ __launch_bounds__(256) void xt_kernel(
    const float* __restrict__ X, __bf16* __restrict__ XT,
    float* __restrict__ out_inc, __bf16* __restrict__ A16)
{
    __shared__ __bf16 tile[64 * 72];             // stride 72 elems = 144 B
    int t = threadIdx.x;
    int ntile = blockIdx.x, b = blockIdx.y;
    int n = t >> 2, q = t & 3;
    const float* src = X + ((size_t)b * NN + ntile * 64 + n) * DD + q * 16;
    #pragma unroll
    for (int v = 0; v < 4; ++v) {
        f32x4 u = *(const f32x4*)(src + v * 4);
        #pragma unroll
        for (int j = 0; j < 4; ++j) {
            int d = q * 16 + v * 4 + j;
            tile[d * 72 + n] = (__bf16)u[j];
        }
    }
    __syncthreads();
    int d = t >> 2;
    __bf16* dst = XT + ((size_t)b * DD + d) * NN + ntile * 64 + q * 16;
    *(bf16x8*)dst       = *(bf16x8*)&tile[d * 72 + q * 16];
    *(bf16x8*)(dst + 8) = *(bf16x8*)&tile[d * 72 + q * 16 + 8];
    if (b == 0 && t < 64) {                      // diagonal of W + I
        int r = ntile * 64 + t;
        out_inc[(size_t)r * NN + r] = 1.0f;
        A16[(size_t)r * NN + r] = (__bf16)1.0f;
    }
}

// ---------------------------------------------------------------------------
// Kernel 3: acc = A16 @ X[b] via MFMA. R4 loop EXACTLY (compute BEFORE
//   stage -- stage-first forces a compiler LDS-alias vmcnt drain each
//   iteration: R9 measured 43.4 -> 76.5 us) + additive-only squeezes:
//   - R = rproj+I pre-staged into dedicated LDS region during prologue
//   - mxa/ssa prefetched to regs at start (drained pre-loop)
//   - XA (X rows) reg-prefetch issued before compute(3) (no LDS aliasing)
//   - phase-2 writes XA from registers; epilogue reads msl from LDS
//   block = 128 rows x 64 cols x 2 batches; 512 thr / 8 waves (2/SIMD);
//   4 x 32 KB LDS buffers, depth-3, ONE s_barrier + vmcnt(8)/k-step,
//   setprio around MFMA.
// ---------------------------------------------------------------------------
__global__ __launch_bounds__(512, 2) void gemm_loss_kernel(
    const __bf16* __restrict__ A16, const __bf16* __restrict__ XT,
    const float* __restrict__ X, const float* __restrict__ rproj,
    const float* __restrict__ mxa, const float* __restrict__ ssa,
    float* __restrict__ loss)
{
    // buffer c at smem + c*16384:  A[128][64] then X[2][64][64] (flat [128][64])
    __shared__ __bf16 smem[4 * 16384];           // 128 KB
    __shared__ __bf16 Rr[64 * 64];               // 8 KB: r + I, swizzled
    __shared__ float  msl[256];                  // mx[128] then ss[128]

    const int t = threadIdx.x;
    const int wave = t >> 6, lane = t & 63;
    const int quad = lane >> 4, ln = lane & 15;
    const int sr = lane >> 3, so = lane & 7;     // staging row-in-group / octet
    const int bq = wave >> 2;                    // batch within pair (0/1)
    const int wr = (wave & 3) << 5;              // wave row offset: 0/32/64/96
    const int m0 = blockIdx.x * 128;
    const int b0 = blockIdx.y * 2;

    const __bf16* Abase = A16 + (size_t)m0 * NN;
    const __bf16* XTb   = XT + (size_t)b0 * DD * NN;   // 2 batches, flat 128 rows

#define FENCE() asm volatile("" ::: "memory")
#define VMCNT(N) asm volatile("s_waitcnt vmcnt(" #N ")" ::: "memory")
#define BAR() do { __builtin_amdgcn_s_barrier(); \
                   __builtin_amdgcn_sched_barrier(0); } while (0)

    // ---- early prefetches (issued before stages -> oldest in vmcnt queue,
    //      fully drained by compiler waits before their pre-loop uses) ----
    float mxv = 0.f, ssv = 0.f;
    if (t < 128) { mxv = mxa[m0 + t]; ssv = ssa[m0 + t]; }
    f32x4 rv0, rv1, rv2, rv3;
    const int rr2 = t >> 2, q2 = t & 3;          // rr2 in [0,64) when t < 256
    if (t < 256) {
        const float* rs = rproj + (size_t)rr2 * DD + q2 * 16;
        rv0 = *(const f32x4*)(rs);
        rv1 = *(const f32x4*)(rs + 4);
        rv2 = *(const f32x4*)(rs + 8);
        rv3 = *(const f32x4*)(rs + 12);
    }
    FENCE();                                     // pin prefetch loads before stages

    f32x4 acc[2][4];
    f32x4 zero = {0.f, 0.f, 0.f, 0.f};
    #pragma unroll
    for (int mt = 0; mt < 2; ++mt)
        #pragma unroll
        for (int ct = 0; ct < 4; ++ct) acc[mt][ct] = zero;

    // stage one 64-wide k-step into buffer `buf`: A 16 KB + X 16 KB,
    // 4 global_load_lds (16 B) per thread, XOR-octet pre-swizzled source.
    auto stage = [&](int buf, int kt) {
        __bf16* bA = smem + buf * 16384;
        __bf16* bX = bA + 8192;
        const int k0 = kt << 6;
        #pragma unroll
        for (int p = 0; p < 2; ++p) {
            const int r0 = (p << 6) + (wave << 3);   // wave-uniform 8-row group
            const int r  = r0 + sr;
            const int og = so ^ (r & 7);             // LDS[r][o] = G[r][o^(r&7)]
            __builtin_amdgcn_global_load_lds(
                (gas_void*)(Abase + (size_t)r * NN + k0 + (og << 3)),
                (las_void*)(bA + r0 * 64), 16, 0, 0);
            __builtin_amdgcn_global_load_lds(
                (gas_void*)(XTb + (size_t)r * NN + k0 + (og << 3)),
                (las_void*)(bX + r0 * 64), 16, 0, 0);
        }
    };

    auto compute = [&](int buf) {
        const __bf16* bA = smem + buf * 16384;
        const __bf16* bX = bA + 8192 + (bq << 12);   // this wave's batch [64][64]
        __builtin_amdgcn_s_setprio(1);
        #pragma unroll
        for (int kk = 0; kk < 64; kk += 32) {
            const int oc = (kk >> 3) + quad;
            bf16x8 af[2], bfr[4];
            #pragma unroll
            for (int mt = 0; mt < 2; ++mt) {
                const int r = wr + mt * 16 + ln;
                af[mt] = *(const bf16x8*)&bA[r * 64 + ((oc ^ (r & 7)) << 3)];
            }
            #pragma unroll
            for (int ct = 0; ct < 4; ++ct) {
                const int n = ct * 16 + ln;
                bfr[ct] = *(const bf16x8*)&bX[n * 64 + ((oc ^ (n & 7)) << 3)];
            }
            #pragma unroll
            for (int mt = 0; mt < 2; ++mt)
                #pragma unroll
                for (int ct = 0; ct < 4; ++ct)
                    acc[mt][ct] = __builtin_amdgcn_mfma_f32_16x16x32_bf16(
                        af[mt], bfr[ct], acc[mt][ct], 0, 0, 0);
        }
        __builtin_amdgcn_s_setprio(0);
    };

    const int NT = NN / 64;                      // 64 k-steps
    stage(0, 0); FENCE();
    stage(1, 1); FENCE();
    stage(2, 2); FENCE();

    // R = rproj + I into dedicated region (overlaps pipeline prologue).
    if (t < 256) {
        #pragma unroll
        for (int v = 0; v < 4; ++v) {
            f32x4 u = v == 0 ? rv0 : v == 1 ? rv1 : v == 2 ? rv2 : rv3;
            #pragma unroll
            for (int j = 0; j < 4; ++j) {
                const int d = q2 * 16 + v * 4 + j;
                float val = u[j] + (d == rr2 ? 1.0f : 0.0f);   // r + I
                Rr[d * 64 + (((rr2 >> 3) ^ (d & 7)) << 3) + (rr2 & 7)] = (__bf16)val;
            }
        }
    }

    for (int kt = 0; kt < NT - 3; ++kt) {        // kt = 0..60
        VMCNT(8);                                // outstanding kt..kt+2 (12); drain kt
        BAR();
        compute(kt & 3);                         // reads BEFORE new stage issue
        stage((kt + 3) & 3, kt + 3);
    }
    VMCNT(8);  BAR(); compute(1);                // kt = 61 (outstanding 61..63)
    VMCNT(4);  BAR(); compute(2);                // kt = 62
    VMCNT(0);  BAR();                            // kt = 63: queue empty

    // XA reg-prefetch (plain global->reg; no LDS alias) under compute(3)
    f32x4 xa[2][2][2];                           // [bb][v][half], static idx
    const int rr = t >> 2, q = t & 3;            // rr in [0,128)
    {
        #pragma unroll
        for (int bb = 0; bb < 2; ++bb) {
            const float* xs = X + ((size_t)(b0 + bb) * NN + m0 + rr) * DD + q * 16;
            #pragma unroll
            for (int v = 0; v < 2; ++v) {
                xa[bb][v][0] = *(const f32x4*)(xs + v * 8);
                xa[bb][v][1] = *(const f32x4*)(xs + v * 8 + 4);
            }
        }
    }
    compute(3);

#undef BAR
#undef VMCNT
#undef FENCE

    __syncthreads();                             // all compute done before reuse

    // ---- phase 2: write XA[2][128][64] from prefetched regs; publish msl ----
    {
        #pragma unroll
        for (int bb = 0; bb < 2; ++bb) {
            __bf16* XA = smem + bb * 8192;
            #pragma unroll
            for (int v = 0; v < 2; ++v) {
                f32x4 u0 = xa[bb][v][0];
                f32x4 u1 = xa[bb][v][1];
                bf16x8 w;
                #pragma unroll
                for (int j = 0; j < 4; ++j) { w[j] = (__bf16)u0[j]; w[j + 4] = (__bf16)u1[j]; }
                const int o = (q * 2 + v) ^ (rr & 7);
                *(bf16x8*)&XA[rr * 64 + o * 8] = w;
            }
        }
        if (t < 128) { msl[t] = mxv; msl[128 + t] = ssv; }
    }
    __syncthreads();

    // ---- xp phase accumulates into -acc: dif = X@(r+I) - acc ----
    #pragma unroll
    for (int mt = 0; mt < 2; ++mt)
        #pragma unroll
        for (int ct = 0; ct < 4; ++ct) acc[mt][ct] = -acc[mt][ct];

    {
        const __bf16* XA = smem + bq * 8192;
        #pragma unroll
        for (int kk = 0; kk < DD; kk += 32) {
            const int oc = (kk >> 3) + quad;
            bf16x8 af[2], bfr[4];
            #pragma unroll
            for (int mt = 0; mt < 2; ++mt) {
                const int r = wr + mt * 16 + ln;
                af[mt] = *(const bf16x8*)&XA[r * 64 + ((oc ^ (r & 7)) << 3)];
            }
            #pragma unroll
            for (int ct = 0; ct < 4; ++ct) {
                const int n = ct * 16 + ln;
                bfr[ct] = *(const bf16x8*)&Rr[n * 64 + ((oc ^ (n & 7)) << 3)];
            }
            #pragma unroll
            for (int mt = 0; mt < 2; ++mt)
                #pragma unroll
                for (int ct = 0; ct < 4; ++ct)
                    acc[mt][ct] = __builtin_amdgcn_mfma_f32_16x16x32_bf16(
                        af[mt], bfr[ct], acc[mt][ct], 0, 0, 0);
        }
    }

    // ---- epilogue: C/D layout col=ln, row=quad*4+reg; wave owns full rows ----
    #pragma unroll
    for (int mt = 0; mt < 2; ++mt) {
        #pragma unroll
        for (int rg = 0; rg < 4; ++rg) {
            float s = 0.f;
            #pragma unroll
            for (int ct = 0; ct < 4; ++ct) {
                float d = acc[mt][ct][rg];
                s += d * d;
            }
            s += __shfl_xor(s, 1);
            s += __shfl_xor(s, 2);
            s += __shfl_xor(s, 4);
            s += __shfl_xor(s, 8);
            if (ln == 0) {
                int rloc = wr + mt * 16 + quad * 4 + rg;
                loss[(size_t)(b0 + bq) * NN + m0 + rloc] =
                    0.2f * sqrtf(s) + msl[rloc] + 0.001f * sqrtf(msl[128 + rloc]);
            }
        }
    }
}

extern "C" void kernel_launch(void* const* d_in, const int* in_sizes, int n_in,
                              void* d_out, int out_size, void* d_ws, size_t ws_size,
                              hipStream_t stream) {
    const float* X   = (const float*)d_in[0];   // [B][N][D] f32
    const float* r   = (const float*)d_in[1];   // [D][D] f32
    const float* inc = (const float*)d_in[2];   // [N][N-1] f32
    float* out      = (float*)d_out;
    float* out_loss = out;                       // [B][N]
    float* out_inc  = out + (size_t)BB * NN;     // [N][N]

    char* ws = (char*)d_ws;
    float*  mxa = (float*)ws;                               // 16 KB
    float*  ssa = (float*)(ws + 16384);                     // 16 KB
    __bf16* XT  = (__bf16*)(ws + 32768);                    //  8 MiB
    __bf16* A16 = (__bf16*)(ws + 32768 + (size_t)8 * 1024 * 1024);  // 32 MiB

    hipMemsetAsync(mxa, 0, 32768, stream);      // zero mx/ss accumulators

    hipLaunchKernelGGL(build_kernel, dim3(NM1), dim3(256), 0, stream,
                       inc, out_inc, A16, mxa, ssa);
    hipLaunchKernelGGL(xt_kernel, dim3(NN / 64, BB), dim3(256), 0, stream,
                       X, XT, out_inc, A16);
    hipLaunchKernelGGL(gemm_loss_kernel, dim3(NN / 128, BB / 2), dim3(512), 0, stream,
                       A16, XT, X, r, mxa, ssa, out_loss);
}

// Round 11
// 185.064 us; speedup vs baseline: 1.1262x; 1.0314x over previous
//
#include <hip/hip_runtime.h>
#include <hip/hip_bf16.h>

#define BB 16
#define NN 4096
#define DD 64
#define NM1 4095

typedef __bf16 bf16x8 __attribute__((ext_vector_type(8)));
typedef float f32x4 __attribute__((ext_vector_type(4)));

typedef __attribute__((address_space(1))) const void gas_void;
typedef __attribute__((address_space(3))) void las_void;

// ws layout:
//   [0]                  float mx[4096]          (16 KB)  -- zeroed via memsetAsync
//   [16384]              float ss[4096]          (16 KB)  -- zeroed via memsetAsync
//   [32768]              __bf16 XT[16][64][4096] ( 8 MiB)
//   [32768 + 8 MiB]      __bf16 A16[4096][4096]  (32 MiB)

// ---------------------------------------------------------------------------
// Kernel 1: flat scatter build. j-major: lane-consecutive loads AND stores.
// ---------------------------------------------------------------------------
__global__ __launch_bounds__(256) void build_kernel(
    const float* __restrict__ inc, float* __restrict__ out_inc,
    __bf16* __restrict__ A16, float* __restrict__ mxa, float* __restrict__ ssa)
{
    int t = threadIdx.x;
    int base = blockIdx.x << 12;                 // 4096 elems per block
    int rA = (int)((unsigned)base / NM1);        // block spans rows {rA, rA+1}
    float pm0 = 0.f, ps0 = 0.f, pm1 = 0.f, ps1 = 0.f;
    #pragma unroll
    for (int j = 0; j < 16; ++j) {
        int f = base + j * 256 + t;              // < 2^24, exact coverage
        int i = (int)((unsigned)f / NM1);
        int c = f - i * NM1;
        float x = inc[f];
        float w = x > 0.01f ? x : 0.f;
        int dst = f + i + (c >= i);              // i*4096 + c + (c>=i)
        out_inc[dst] = w;
        A16[dst] = (__bf16)w;
        if (i == rA) { pm0 = fmaxf(pm0, w); ps0 += w * w; }
        else         { pm1 = fmaxf(pm1, w); ps1 += w * w; }
    }
    #pragma unroll
    for (int off = 32; off; off >>= 1) {
        pm0 = fmaxf(pm0, __shfl_down(pm0, off));
        ps0 += __shfl_down(ps0, off);
        pm1 = fmaxf(pm1, __shfl_down(pm1, off));
        ps1 += __shfl_down(ps1, off);
    }
    __shared__ float sm0[4], sq0[4], sm1[4], sq1[4];
    int wid = t >> 6;
    if ((t & 63) == 0) { sm0[wid] = pm0; sq0[wid] = ps0; sm1[wid] = pm1; sq1[wid] = ps1; }
    __syncthreads();
    if (t == 0) {
        float m0v = fmaxf(fmaxf(sm0[0], sm0[1]), fmaxf(sm0[2], sm0[3]));
        float s0v = sq0[0] + sq0[1] + sq0[2] + sq0[3];
        float m1v = fmaxf(fmaxf(sm1[0], sm1[1]), fmaxf(sm1[2], sm1[3]));
        float s1v = sq1[0] + sq1[1] + sq1[2] + sq1[3];
        atomicMax((unsigned*)(mxa + rA), __float_as_uint(m0v));  // w >= 0
        atomicAdd(ssa + rA, s0v);
        int rB = rA + 1;
        if (rB < NN) {
            atomicMax((unsigned*)(mxa + rB), __float_as_uint(m1v));
            atomicAdd(ssa + rB, s1v);
        }
    }
}

// ---------------------------------------------------------------------------
// Kernel 2: XT[b][d][n] = (bf16)X[b][n][d]  (64x64 tiles via LDS) + diagonal
// ---------------------------------------------------------------------------
__global__ __launch_bounds__(256) void xt_kernel(
    const float* __restrict__ X, __bf16* __restrict__ XT,
    float* __restrict__ out_inc, __bf16* __restrict__ A16)
{
    __shared__ __bf16 tile[64 * 72];             // stride 72 elems = 144 B
    int t = threadIdx.x;
    int ntile = blockIdx.x, b = blockIdx.y;
    int n = t >> 2, q = t & 3;
    const float* src = X + ((size_t)b * NN + ntile * 64 + n) * DD + q * 16;
    #pragma unroll
    for (int v = 0; v < 4; ++v) {
        f32x4 u = *(const f32x4*)(src + v * 4);
        #pragma unroll
        for (int j = 0; j < 4; ++j) {
            int d = q * 16 + v * 4 + j;
            tile[d * 72 + n] = (__bf16)u[j];
        }
    }
    __syncthreads();
    int d = t >> 2;
    __bf16* dst = XT + ((size_t)b * DD + d) * NN + ntile * 64 + q * 16;
    *(bf16x8*)dst       = *(bf16x8*)&tile[d * 72 + q * 16];
    *(bf16x8*)(dst + 8) = *(bf16x8*)&tile[d * 72 + q * 16 + 8];
    if (b == 0 && t < 64) {                      // diagonal of W + I
        int r = ntile * 64 + t;
        out_inc[(size_t)r * NN + r] = 1.0f;
        A16[(size_t)r * NN + r] = (__bf16)1.0f;
    }
}

// ---------------------------------------------------------------------------
// Kernel 3: acc = A16 @ X[b] via MFMA (R1 structure + deeper pipeline).
//   block = 128 rows x 64 cols x 2 batches; 512 thr / 8 waves (2/SIMD);
//   wave = 32 rows x 64 cols of one batch.
//   4 x 32 KB LDS buffers, prefetch depth 3, steady vmcnt(8), ONE raw
//   s_barrier per k-step (stage(kt+3) issued AFTER compute(kt): buffer
//   (kt+3)&3 == (kt-1)&3 was last read before barrier#kt -> safe).
//   s_setprio(1) around MFMA cluster. Fused xp phase: dif = xp - acc.
//   NOTE: compute BEFORE stage is load-bearing -- stage-first forces a
//   compiler LDS-alias vmcnt drain each iteration (R9: 43.4 -> 76.5 us).
// ---------------------------------------------------------------------------
__global__ __launch_bounds__(512, 2) void gemm_loss_kernel(
    const __bf16* __restrict__ A16, const __bf16* __restrict__ XT,
    const float* __restrict__ X, const float* __restrict__ rproj,
    const float* __restrict__ mxa, const float* __restrict__ ssa,
    float* __restrict__ loss)
{
    // buffer c at smem + c*16384:  A[128][64] then X[2][64][64] (flat [128][64])
    __shared__ __bf16 smem[4 * 16384];           // 128 KB

    const int t = threadIdx.x;
    const int wave = t >> 6, lane = t & 63;
    const int quad = lane >> 4, ln = lane & 15;
    const int sr = lane >> 3, so = lane & 7;     // staging row-in-group / octet
    const int bq = wave >> 2;                    // batch within pair (0/1)
    const int wr = (wave & 3) << 5;              // wave row offset: 0/32/64/96
    const int m0 = blockIdx.x * 128;
    const int b0 = blockIdx.y * 2;

    const __bf16* Abase = A16 + (size_t)m0 * NN;
    const __bf16* XTb   = XT + (size_t)b0 * DD * NN;   // 2 batches, flat 128 rows

    f32x4 acc[2][4];
    f32x4 zero = {0.f, 0.f, 0.f, 0.f};
    #pragma unroll
    for (int mt = 0; mt < 2; ++mt)
        #pragma unroll
        for (int ct = 0; ct < 4; ++ct) acc[mt][ct] = zero;

    // stage one 64-wide k-step into buffer `buf`: A 16 KB + X 16 KB,
    // 4 global_load_lds (16 B) per thread, XOR-octet pre-swizzled source.
    auto stage = [&](int buf, int kt) {
        __bf16* bA = smem + buf * 16384;
        __bf16* bX = bA + 8192;
        const int k0 = kt << 6;
        #pragma unroll
        for (int p = 0; p < 2; ++p) {
            const int r0 = (p << 6) + (wave << 3);   // wave-uniform 8-row group
            const int r  = r0 + sr;
            const int og = so ^ (r & 7);             // LDS[r][o] = G[r][o^(r&7)]
            __builtin_amdgcn_global_load_lds(
                (gas_void*)(Abase + (size_t)r * NN + k0 + (og << 3)),
                (las_void*)(bA + r0 * 64), 16, 0, 0);
            __builtin_amdgcn_global_load_lds(
                (gas_void*)(XTb + (size_t)r * NN + k0 + (og << 3)),
                (las_void*)(bX + r0 * 64), 16, 0, 0);
        }
    };

    auto compute = [&](int buf) {
        const __bf16* bA = smem + buf * 16384;
        const __bf16* bX = bA + 8192 + (bq << 12);   // this wave's batch [64][64]
        __builtin_amdgcn_s_setprio(1);
        #pragma unroll
        for (int kk = 0; kk < 64; kk += 32) {
            const int oc = (kk >> 3) + quad;
            bf16x8 af[2], bfr[4];
            #pragma unroll
            for (int mt = 0; mt < 2; ++mt) {
                const int r = wr + mt * 16 + ln;
                af[mt] = *(const bf16x8*)&bA[r * 64 + ((oc ^ (r & 7)) << 3)];
            }
            #pragma unroll
            for (int ct = 0; ct < 4; ++ct) {
                const int n = ct * 16 + ln;
                bfr[ct] = *(const bf16x8*)&bX[n * 64 + ((oc ^ (n & 7)) << 3)];
            }
            #pragma unroll
            for (int mt = 0; mt < 2; ++mt)
                #pragma unroll
                for (int ct = 0; ct < 4; ++ct)
                    acc[mt][ct] = __builtin_amdgcn_mfma_f32_16x16x32_bf16(
                        af[mt], bfr[ct], acc[mt][ct], 0, 0, 0);
        }
        __builtin_amdgcn_s_setprio(0);
    };

    const int NT = NN / 64;                      // 64 k-steps
    stage(0, 0);
    stage(1, 1);
    stage(2, 2);
    for (int kt = 0; kt < NT - 3; ++kt) {        // kt = 0..60
        asm volatile("s_waitcnt vmcnt(8)" ::: "memory");
        __builtin_amdgcn_s_barrier();
        __builtin_amdgcn_sched_barrier(0);
        compute(kt & 3);
        stage((kt + 3) & 3, kt + 3);
    }
    // kt = 61
    asm volatile("s_waitcnt vmcnt(8)" ::: "memory");
    __builtin_amdgcn_s_barrier();
    __builtin_amdgcn_sched_barrier(0);
    compute(1);
    // kt = 62
    asm volatile("s_waitcnt vmcnt(4)" ::: "memory");
    __builtin_amdgcn_s_barrier();
    __builtin_amdgcn_sched_barrier(0);
    compute(2);
    // kt = 63
    asm volatile("s_waitcnt vmcnt(0)" ::: "memory");
    __builtin_amdgcn_s_barrier();
    __builtin_amdgcn_sched_barrier(0);
    compute(3);

    __syncthreads();                             // all compute done before reuse

    // ---- phase 2 staging: XA[2][128][64] = bf16(X rows), R[64][64] = r+I ----
    {
        const int rr = t >> 2, q = t & 3;        // rr in [0,128)
        #pragma unroll
        for (int bb = 0; bb < 2; ++bb) {
            const float* xs = X + ((size_t)(b0 + bb) * NN + m0 + rr) * DD + q * 16;
            __bf16* XA = smem + bb * 8192;
            #pragma unroll
            for (int v = 0; v < 2; ++v) {
                f32x4 u0 = *(const f32x4*)(xs + v * 8);
                f32x4 u1 = *(const f32x4*)(xs + v * 8 + 4);
                bf16x8 w;
                #pragma unroll
                for (int j = 0; j < 4; ++j) { w[j] = (__bf16)u0[j]; w[j + 4] = (__bf16)u1[j]; }
                const int o = (q * 2 + v) ^ (rr & 7);
                *(bf16x8*)&XA[rr * 64 + o * 8] = w;
            }
        }
        if (t < 256) {
            const int rr2 = t >> 2, q2 = t & 3;  // rr2 in [0,64): rproj row e
            const float* rs = rproj + (size_t)rr2 * DD + q2 * 16;
            __bf16* R = smem + 16384;
            #pragma unroll
            for (int v = 0; v < 4; ++v) {
                f32x4 u = *(const f32x4*)(rs + v * 4);
                #pragma unroll
                for (int j = 0; j < 4; ++j) {
                    const int d = q2 * 16 + v * 4 + j;
                    float val = u[j] + (d == rr2 ? 1.0f : 0.0f);   // r + I
                    R[d * 64 + (((rr2 >> 3) ^ (d & 7)) << 3) + (rr2 & 7)] = (__bf16)val;
                }
            }
        }
    }
    __syncthreads();

    // ---- xp phase accumulates into -acc: dif = X@(r+I) - acc ----
    #pragma unroll
    for (int mt = 0; mt < 2; ++mt)
        #pragma unroll
        for (int ct = 0; ct < 4; ++ct) acc[mt][ct] = -acc[mt][ct];

    {
        const __bf16* XA = smem + bq * 8192;
        const __bf16* R  = smem + 16384;
        #pragma unroll
        for (int kk = 0; kk < DD; kk += 32) {
            const int oc = (kk >> 3) + quad;
            bf16x8 af[2], bfr[4];
            #pragma unroll
            for (int mt = 0; mt < 2; ++mt) {
                const int r = wr + mt * 16 + ln;
                af[mt] = *(const bf16x8*)&XA[r * 64 + ((oc ^ (r & 7)) << 3)];
            }
            #pragma unroll
            for (int ct = 0; ct < 4; ++ct) {
                const int n = ct * 16 + ln;
                bfr[ct] = *(const bf16x8*)&R[n * 64 + ((oc ^ (n & 7)) << 3)];
            }
            #pragma unroll
            for (int mt = 0; mt < 2; ++mt)
                #pragma unroll
                for (int ct = 0; ct < 4; ++ct)
                    acc[mt][ct] = __builtin_amdgcn_mfma_f32_16x16x32_bf16(
                        af[mt], bfr[ct], acc[mt][ct], 0, 0, 0);
        }
    }

    // ---- epilogue: C/D layout col=ln, row=quad*4+reg; wave owns full rows ----
    #pragma unroll
    for (int mt = 0; mt < 2; ++mt) {
        #pragma unroll
        for (int rg = 0; rg < 4; ++rg) {
            float s = 0.f;
            #pragma unroll
            for (int ct = 0; ct < 4; ++ct) {
                float d = acc[mt][ct][rg];
                s += d * d;
            }
            s += __shfl_xor(s, 1);
            s += __shfl_xor(s, 2);
            s += __shfl_xor(s, 4);
            s += __shfl_xor(s, 8);
            if (ln == 0) {
                int row = m0 + wr + mt * 16 + quad * 4 + rg;
                loss[(size_t)(b0 + bq) * NN + row] =
                    0.2f * sqrtf(s) + mxa[row] + 0.001f * sqrtf(ssa[row]);
            }
        }
    }
}

extern "C" void kernel_launch(void* const* d_in, const int* in_sizes, int n_in,
                              void* d_out, int out_size, void* d_ws, size_t ws_size,
                              hipStream_t stream) {
    const float* X   = (const float*)d_in[0];   // [B][N][D] f32
    const float* r   = (const float*)d_in[1];   // [D][D] f32
    const float* inc = (const float*)d_in[2];   // [N][N-1] f32
    float* out      = (float*)d_out;
    float* out_loss = out;                       // [B][N]
    float* out_inc  = out + (size_t)BB * NN;     // [N][N]

    char* ws = (char*)d_ws;
    float*  mxa = (float*)ws;                               // 16 KB
    float*  ssa = (float*)(ws + 16384);                     // 16 KB
    __bf16* XT  = (__bf16*)(ws + 32768);                    //  8 MiB
    __bf16* A16 = (__bf16*)(ws + 32768 + (size_t)8 * 1024 * 1024);  // 32 MiB

    hipMemsetAsync(mxa, 0, 32768, stream);      // zero mx/ss accumulators

    hipLaunchKernelGGL(build_kernel, dim3(NM1), dim3(256), 0, stream,
                       inc, out_inc, A16, mxa, ssa);
    hipLaunchKernelGGL(xt_kernel, dim3(NN / 64, BB), dim3(256), 0, stream,
                       X, XT, out_inc, A16);
    hipLaunchKernelGGL(gemm_loss_kernel, dim3(NN / 128, BB / 2), dim3(512), 0, stream,
                       A16, XT, X, r, mxa, ssa, out_loss);
}